// Round 6
// baseline (269.287 us; speedup 1.0000x reference)
//
#include <hip/hip_runtime.h>
#include <math.h>

// ConvCapsule R6 = R3 + {8 blocks/CU occupancy, transpose bank-swizzle, fast rcp/rsq}.
// bf16-MFMA per-pixel conv + fused 3-iter dynamic routing; votes in registers
// (one vote-row per thread after LDS transpose); DPP 8-lane reductions.
// LDS 20480 B = exactly 8 blocks/CU; VGPR capped <=64 via __launch_bounds__(256,8).

using short8 = __attribute__((ext_vector_type(8))) short;
using f32x4  = __attribute__((ext_vector_type(4))) float;

__device__ __forceinline__ unsigned short f2bf(float f) {
    unsigned u = __float_as_uint(f);
    return (unsigned short)((u + 0x7fffu + ((u >> 16) & 1u)) >> 16);  // RNE
}

// DPP helpers: 8-lane-group reductions (lanes differing in bits 0..2).
template<int CTRL>
__device__ __forceinline__ float dpp_movf(float x) {
    return __int_as_float(__builtin_amdgcn_update_dpp(
        0, __float_as_int(x), CTRL, 0xF, 0xF, true));
}
__device__ __forceinline__ float sum8(float x) {
    x += dpp_movf<0xB1>(x);    // quad_perm [1,0,3,2]  (xor1)
    x += dpp_movf<0x4E>(x);    // quad_perm [2,3,0,1]  (xor2)
    x += dpp_movf<0x141>(x);   // row_half_mirror      (xor4 within 8)
    return x;
}
__device__ __forceinline__ float max8(float x) {
    x = fmaxf(x, dpp_movf<0xB1>(x));
    x = fmaxf(x, dpp_movf<0x4E>(x));
    x = fmaxf(x, dpp_movf<0x141>(x));
    return x;
}

// ---------- prep 1: W -> bf16, [s(7)][g(4)][oa(256)][j(8)], k = s*32+g*8+j ----------
__global__ __launch_bounds__(256)
void prep_w(const float* __restrict__ cw, unsigned short* __restrict__ wp) {
    const int idx = blockIdx.x * 256 + threadIdx.x;   // 57344 total
    const int j  = idx & 7;
    const int oa = (idx >> 3) & 255;
    const int g  = (idx >> 11) & 3;
    const int s  = idx >> 13;
    const int k  = s * 32 + g * 8 + j;
    wp[idx] = (k < 200) ? f2bf(cw[k * 256 + oa]) : (unsigned short)0;
}

// ---------- prep 2: x -> bf16 transposed [b][y][x][i*8+ci] ----------
__global__ __launch_bounds__(256)
void prep_x(const float* __restrict__ x, unsigned short* __restrict__ xt) {
    __shared__ unsigned short tile[32 * 256];         // [xx][plane]
    const int t = threadIdx.x;                        // plane = i*8+ci
    const int b = blockIdx.x >> 5, y = blockIdx.x & 31;
    const float* src = x + (((size_t)((b << 8) + t)) << 10) + (y << 5);
    #pragma unroll
    for (int c = 0; c < 8; ++c) {
        float4 v = *(const float4*)(src + c * 4);
        tile[(c * 4 + 0) * 256 + t] = f2bf(v.x);
        tile[(c * 4 + 1) * 256 + t] = f2bf(v.y);
        tile[(c * 4 + 2) * 256 + t] = f2bf(v.z);
        tile[(c * 4 + 3) * 256 + t] = f2bf(v.w);
    }
    __syncthreads();
    unsigned short* dst = xt + ((size_t)blockIdx.x << 13);   // (b*32+y)*8192
    #pragma unroll
    for (int c = 0; c < 4; ++c) {
        const int chunk = t + c * 256;
        *(short8*)(dst + chunk * 8) = *(const short8*)(&tile[chunk * 8]);
    }
}

// ---------- main fused kernel ----------
__global__ __launch_bounds__(256, 8)
void capsule_mfma(const unsigned short* __restrict__ xt,
                  const unsigned short* __restrict__ wp,
                  const float* __restrict__ conv_b,
                  const float* __restrict__ biases,
                  float* __restrict__ out)
{
    // Overlaid LDS phases (20480 B = 8 blocks/CU exactly):
    //   A: patch  [32 i][232 k] bf16 (14848 B)   — conv B-operand
    //   B: vtr    per-wave float[64][20] (4*5120) — C transpose (chunk-rotated)
    //   C: route_T float[32][36] @0 ; logits_T float[32][36] @4608
    __shared__ __align__(16) char lds[20480];
    float* route_T  = (float*)lds;
    float* logits_T = (float*)(lds + 4608);

    const int t   = threadIdx.x;
    const int blk = blockIdx.x;
    const int b   = blk >> 10;
    const int pix = blk & 1023;
    const int h   = pix >> 5;
    const int w   = pix & 31;

    // ---- zero-pad patch k in [200,232) ----
    if (t < 128) {
        const int i = t >> 2, c = t & 3;
        *(f32x4*)(lds + i * 464 + 400 + c * 16) = (f32x4){0.f, 0.f, 0.f, 0.f};
    }

    // ---- stage patch: unit u = (p, i); lane loads 8 ci (16B) coalesced ----
    for (int u = t; u < 800; u += 256) {
        const int i = u & 31, p = u >> 5;
        const int ky = p / 5, kx = p - ky * 5;
        const int y = h + ky - 2, xx = w + kx - 2;
        short8 v = {0, 0, 0, 0, 0, 0, 0, 0};
        if ((unsigned)y < 32u && (unsigned)xx < 32u)
            v = *(const short8*)(xt + (((size_t)(((b << 5) + y) << 5) + xx) << 8) + i * 8);
        *(short8*)(lds + i * 464 + p * 16) = v;       // patch[i][k=p*8..p*8+7]
    }

    // ---- conv: M=oa (A=W), N=i (B=patch), K=224 (7 steps of 32) ----
    const int l  = t & 63, wv = t >> 6;
    const int lm = l & 15, lg = l >> 4;

    f32x4 acc[4][2];
    #pragma unroll
    for (int mt = 0; mt < 4; ++mt)
        #pragma unroll
        for (int ti = 0; ti < 2; ++ti)
            acc[mt][ti] = (f32x4){0.f, 0.f, 0.f, 0.f};

    __syncthreads();   // patch ready

    // A-frag source: wp[s][g=lg][oa = wv*64 + mt*16 + lm][j]
    const unsigned short* wbase = wp + lg * 2048 + (((wv << 2) << 4) + lm) * 8;

    short8 a_cur[4], a_nxt[4];
    #pragma unroll
    for (int mt = 0; mt < 4; ++mt)
        a_cur[mt] = *(const short8*)(wbase + mt * 128);

    for (int s = 0; s < 7; ++s) {
        if (s < 6) {
            #pragma unroll
            for (int mt = 0; mt < 4; ++mt)
                a_nxt[mt] = *(const short8*)(wbase + (s + 1) * 8192 + mt * 128);
        }
        const short8 b0 = *(const short8*)(lds + lm * 464 + s * 64 + lg * 16);
        const short8 b1 = *(const short8*)(lds + (16 + lm) * 464 + s * 64 + lg * 16);
        #pragma unroll
        for (int mt = 0; mt < 4; ++mt) {
            acc[mt][0] = __builtin_amdgcn_mfma_f32_16x16x32_bf16(a_cur[mt], b0, acc[mt][0], 0, 0, 0);
            acc[mt][1] = __builtin_amdgcn_mfma_f32_16x16x32_bf16(a_cur[mt], b1, acc[mt][1], 0, 0, 0);
        }
        #pragma unroll
        for (int mt = 0; mt < 4; ++mt) a_cur[mt] = a_nxt[mt];
    }

    __syncthreads();   // all waves done reading patch; lds reusable

    // ---- transpose C through per-wave LDS region: thread t gets v[i]=vote[oa=t][i] ----
    // Chunk-rotation swizzle: logical 4-float chunk c of row r is stored at
    // physical chunk (c + (r>>3)) & 3 -> reader lanes l, l+8 hit different
    // bank quads (was 8-way conflict at stride 20).
    float v[32];
    float* vtr = (float*)(lds) + wv * 1280;           // [64][20] floats per wave
    #pragma unroll
    for (int ti = 0; ti < 2; ++ti) {
        #pragma unroll
        for (int mt = 0; mt < 4; ++mt)
            #pragma unroll
            for (int r = 0; r < 4; ++r) {
                const int row = mt * 16 + lg * 4 + r;
                vtr[row * 20 + ((((lm >> 2) + (row >> 3)) & 3) << 2) + (lm & 3)] =
                    acc[mt][ti][r];
            }
        __syncthreads();
        #pragma unroll
        for (int c = 0; c < 4; ++c) {
            const f32x4 vv = *(const f32x4*)(vtr + l * 20 + (((c + (l >> 3)) & 3) << 2));
            v[ti * 16 + c * 4 + 0] = vv[0];
            v[ti * 16 + c * 4 + 1] = vv[1];
            v[ti * 16 + c * 4 + 2] = vv[2];
            v[ti * 16 + c * 4 + 3] = vv[3];
        }
        __syncthreads();
    }

    // fold conv bias; iteration-0 route is uniformly 1/33 -> just need rowsum
    const float cb = conv_b[t];
    float rowsum = 0.f;
    #pragma unroll
    for (int i = 0; i < 32; ++i) { v[i] += cb; rowsum += v[i]; }

    const int o_t = t >> 3, a_t = t & 7;
    const float bias_v = biases[t];
    float actv = 0.f;

    #pragma unroll
    for (int it = 0; it < 3; ++it) {
        // ---- preact[o_t][a_t] ----
        float pre;
        if (it == 0) {
            pre = fmaf(rowsum, 1.f / 33.f, bias_v);
        } else {
            pre = bias_v;
            const float* rrow = route_T + o_t * 36;
            #pragma unroll
            for (int c = 0; c < 8; ++c) {
                const f32x4 rv = *(const f32x4*)(rrow + c * 4);   // broadcast (8 lanes/addr)
                pre = fmaf(v[c * 4 + 0], rv[0], pre);
                pre = fmaf(v[c * 4 + 1], rv[1], pre);
                pre = fmaf(v[c * 4 + 2], rv[2], pre);
                pre = fmaf(v[c * 4 + 3], rv[3], pre);
            }
        }

        // ---- squash over the 8-atom group (DPP); fast rsq/rcp ----
        const float ns = sum8(pre * pre);
        // pre * sqrt(ns) / (1+ns) = pre * ns * rsq(ns) * rcp(1+ns)
        actv = pre * ns * __builtin_amdgcn_rsqf(ns) * __builtin_amdgcn_rcpf(1.f + ns);

        if (it < 2) {
            // ---- logits[i][o_t] += sum_a v[i]*act (DPP a-reduce, a==0 lane writes) ----
            float dsum[32];
            #pragma unroll
            for (int i = 0; i < 32; ++i)
                dsum[i] = sum8(v[i] * actv);
            if (a_t == 0) {
                float* lrow = logits_T + o_t * 36;
                #pragma unroll
                for (int c = 0; c < 8; ++c) {
                    f32x4 cur = (it == 0) ? (f32x4){0.f, 0.f, 0.f, 0.f}
                                          : *(const f32x4*)(lrow + c * 4);
                    cur[0] += dsum[c * 4 + 0];
                    cur[1] += dsum[c * 4 + 1];
                    cur[2] += dsum[c * 4 + 2];
                    cur[3] += dsum[c * 4 + 3];
                    *(f32x4*)(lrow + c * 4) = cur;
                }
            }
            __syncthreads();

            // ---- leaky softmax over o for row i=o_t (8 sub-lanes x 4 o's) ----
            const int r = o_t, sub = a_t;
            float e0 = logits_T[(sub * 4 + 0) * 36 + r];
            float e1 = logits_T[(sub * 4 + 1) * 36 + r];
            float e2 = logits_T[(sub * 4 + 2) * 36 + r];
            float e3 = logits_T[(sub * 4 + 3) * 36 + r];
            float mx = fmaxf(fmaxf(e0, e1), fmaxf(e2, e3));
            mx = max8(fmaxf(mx, 0.f));                // include leak logit 0
            e0 = __expf(e0 - mx); e1 = __expf(e1 - mx);
            e2 = __expf(e2 - mx); e3 = __expf(e3 - mx);
            const float ssum = sum8(e0 + e1 + e2 + e3) + __expf(-mx);
            const float inv = __builtin_amdgcn_rcpf(ssum);
            route_T[(sub * 4 + 0) * 36 + r] = e0 * inv;
            route_T[(sub * 4 + 1) * 36 + r] = e1 * inv;
            route_T[(sub * 4 + 2) * 36 + r] = e2 * inv;
            route_T[(sub * 4 + 3) * 36 + r] = e3 * inv;
            __syncthreads();
        }
    }

    // out[b][o][h][w][a]
    out[(((size_t)(((b << 5) + o_t) << 10) + pix) << 3) + a_t] = actv;
}

extern "C" void kernel_launch(void* const* d_in, const int* in_sizes, int n_in,
                              void* d_out, int out_size, void* d_ws, size_t ws_size,
                              hipStream_t stream) {
    const float* x      = (const float*)d_in[0];
    const float* conv_w = (const float*)d_in[1];
    const float* conv_b = (const float*)d_in[2];
    const float* biases = (const float*)d_in[3];
    unsigned short* wp = (unsigned short*)d_ws;                     // 114,688 B
    unsigned short* xt = (unsigned short*)((char*)d_ws + 131072);   // 4 MB
    prep_w<<<dim3(224), dim3(256), 0, stream>>>(conv_w, wp);
    prep_x<<<dim3(256), dim3(256), 0, stream>>>(x, xt);
    capsule_mfma<<<dim3(8192), dim3(256), 0, stream>>>(xt, wp, conv_b, biases, (float*)d_out);
}

// Round 7
// 85.079 us; speedup vs baseline: 3.1651x; 3.1651x over previous
//
#include <hip/hip_runtime.h>
#include <math.h>

// ConvCapsule R7: 2 pixels per 512-thread block (4096 blocks).
// Per-thread structure IDENTICAL to R3 (one (pixel,oa) pair, one vote-row) --
// R4's spill came from 2 rows/thread; R6's from a 32-VGPR launch_bounds cap.
// Wins vs R3: weight L2 traffic halved, patch staging 30 taps/2px (was 25/px),
// LDS 40960B -> 4 blocks/CU (32 waves) possible, swizzled transpose, fast rcp/rsq.

using short8 = __attribute__((ext_vector_type(8))) short;
using f32x4  = __attribute__((ext_vector_type(4))) float;

__device__ __forceinline__ unsigned short f2bf(float f) {
    unsigned u = __float_as_uint(f);
    return (unsigned short)((u + 0x7fffu + ((u >> 16) & 1u)) >> 16);  // RNE
}

template<int CTRL>
__device__ __forceinline__ float dpp_movf(float x) {
    return __int_as_float(__builtin_amdgcn_update_dpp(
        0, __float_as_int(x), CTRL, 0xF, 0xF, true));
}
__device__ __forceinline__ float sum8(float x) {
    x += dpp_movf<0xB1>(x);    // xor1
    x += dpp_movf<0x4E>(x);    // xor2
    x += dpp_movf<0x141>(x);   // xor4 (row_half_mirror)
    return x;
}
__device__ __forceinline__ float max8(float x) {
    x = fmaxf(x, dpp_movf<0xB1>(x));
    x = fmaxf(x, dpp_movf<0x4E>(x));
    x = fmaxf(x, dpp_movf<0x141>(x));
    return x;
}

// ---------- prep 1: W -> bf16, [s(7)][g(4)][oa(256)][j(8)], k = s*32+g*8+j ----------
__global__ __launch_bounds__(256)
void prep_w(const float* __restrict__ cw, unsigned short* __restrict__ wp) {
    const int idx = blockIdx.x * 256 + threadIdx.x;   // 57344 total
    const int j  = idx & 7;
    const int oa = (idx >> 3) & 255;
    const int g  = (idx >> 11) & 3;
    const int s  = idx >> 13;
    const int k  = s * 32 + g * 8 + j;
    wp[idx] = (k < 200) ? f2bf(cw[k * 256 + oa]) : (unsigned short)0;
}

// ---------- prep 2: x -> bf16 transposed [b][y][x][i*8+ci] ----------
__global__ __launch_bounds__(256)
void prep_x(const float* __restrict__ x, unsigned short* __restrict__ xt) {
    __shared__ unsigned short tile[32 * 256];         // [xx][plane]
    const int t = threadIdx.x;                        // plane = i*8+ci
    const int b = blockIdx.x >> 5, y = blockIdx.x & 31;
    const float* src = x + (((size_t)((b << 8) + t)) << 10) + (y << 5);
    #pragma unroll
    for (int c = 0; c < 8; ++c) {
        float4 v = *(const float4*)(src + c * 4);
        tile[(c * 4 + 0) * 256 + t] = f2bf(v.x);
        tile[(c * 4 + 1) * 256 + t] = f2bf(v.y);
        tile[(c * 4 + 2) * 256 + t] = f2bf(v.z);
        tile[(c * 4 + 3) * 256 + t] = f2bf(v.w);
    }
    __syncthreads();
    unsigned short* dst = xt + ((size_t)blockIdx.x << 13);
    #pragma unroll
    for (int c = 0; c < 4; ++c) {
        const int chunk = t + c * 256;
        *(short8*)(dst + chunk * 8) = *(const short8*)(&tile[chunk * 8]);
    }
}

// ---------- main fused kernel: 2 pixels / 512 threads / 8 waves ----------
__global__ __launch_bounds__(512, 4)
void capsule_mfma2(const unsigned short* __restrict__ xt,
                   const unsigned short* __restrict__ wp,
                   const float* __restrict__ conv_b,
                   const float* __restrict__ biases,
                   float* __restrict__ out)
{
    // Overlaid LDS phases (40960 B -> 4 blocks/CU):
    //   A: patch [32 i][31 pos slots][8 ci] bf16, row stride 496 B (15872 B)
    //      pos = ky*6+xl, ky in [0,5), xl in [0,6)  (5x6 window for 2 pixels)
    //   B: vtr per-wave float[64][20], chunk-rotated (8 x 5120 = 40960 B)
    //   C: route_T[q] @ q*4608 ; logits_T[q] @ 9216 + q*4608  (18432 B)
    __shared__ __align__(16) char lds[40960];

    const int t   = threadIdx.x;
    const int blk = blockIdx.x;           // 4096
    const int b   = blk >> 9;
    const int rem = blk & 511;
    const int h   = rem >> 4;
    const int w0  = (rem & 15) << 1;      // pixels w0, w0+1

    // ---- stage patch: 30 pos x 32 i units, 16B each ----
    for (int u = t; u < 960; u += 512) {
        const int i = u & 31, pos = u >> 5;     // pos in [0,30)
        const int ky = pos / 6, xl = pos - ky * 6;
        const int y = h + ky - 2, xx = w0 + xl - 2;
        short8 v = {0, 0, 0, 0, 0, 0, 0, 0};
        if ((unsigned)y < 32u && (unsigned)xx < 32u)
            v = *(const short8*)(xt + (((size_t)(((b << 5) + y) << 5) + xx) << 8) + i * 8);
        *(short8*)(lds + i * 496 + pos * 16) = v;
    }

    const int l  = t & 63, wv = t >> 6;   // 8 waves
    const int lm = l & 15, lg = l >> 4;
    const int qw = wv >> 2;               // wave's pixel (conv phase)

    // conv: M=oa (A=W, wave owns 64 oa), N=i (B=patch), K=224
    f32x4 acc[4][2];
    #pragma unroll
    for (int mt = 0; mt < 4; ++mt)
        #pragma unroll
        for (int ti = 0; ti < 2; ++ti)
            acc[mt][ti] = (f32x4){0.f, 0.f, 0.f, 0.f};

    __syncthreads();   // patch ready

    const unsigned short* wbase = wp + lg * 2048 + ((((wv & 3) << 6) + lm) << 3);

    #pragma unroll
    for (int s = 0; s < 7; ++s) {
        short8 a[4];
        #pragma unroll
        for (int mt = 0; mt < 4; ++mt)
            a[mt] = *(const short8*)(wbase + s * 8192 + mt * 128);
        const int kt = s * 4 + lg;        // tap; k = s*32+lg*8+j
        int pos = 0;
        if (kt <= 24) { const int ky = kt / 5; pos = ky * 6 + (kt - ky * 5); }
        // kt>24: W slice is zero -> patch junk contributes 0
        const char* bb = lds + (pos + qw) * 16;
        const short8 b0 = *(const short8*)(bb + lm * 496);
        const short8 b1 = *(const short8*)(bb + (16 + lm) * 496);
        #pragma unroll
        for (int mt = 0; mt < 4; ++mt) {
            acc[mt][0] = __builtin_amdgcn_mfma_f32_16x16x32_bf16(a[mt], b0, acc[mt][0], 0, 0, 0);
            acc[mt][1] = __builtin_amdgcn_mfma_f32_16x16x32_bf16(a[mt], b1, acc[mt][1], 0, 0, 0);
        }
    }

    __syncthreads();   // all patch reads done; lds reusable for vtr

    // ---- transpose via per-wave vtr (chunk-rotated): thread t -> vote row ----
    // C layout: lane (lm,lg) reg r of acc[mt][ti] = votes[oa_l=mt*16+lg*4+r][i=ti*16+lm]
    float v[32];
    float* vtr = (float*)lds + wv * 1280;             // [64][20]
    #pragma unroll
    for (int ti = 0; ti < 2; ++ti) {
        #pragma unroll
        for (int mt = 0; mt < 4; ++mt)
            #pragma unroll
            for (int r = 0; r < 4; ++r) {
                const int row = mt * 16 + (lg << 2) + r;
                vtr[row * 20 + ((((lm >> 2) + (row >> 3)) & 3) << 2) + (lm & 3)] =
                    acc[mt][ti][r];
            }
        __syncthreads();
        // reading wave r reads its own vtr: row = l (see derivation in journal)
        #pragma unroll
        for (int c = 0; c < 4; ++c) {
            const f32x4 vv = *(const f32x4*)(vtr + l * 20 + (((c + (l >> 3)) & 3) << 2));
            v[ti * 16 + c * 4 + 0] = vv[0];
            v[ti * 16 + c * 4 + 1] = vv[1];
            v[ti * 16 + c * 4 + 2] = vv[2];
            v[ti * 16 + c * 4 + 3] = vv[3];
        }
        __syncthreads();
    }

    // ---- routing: thread t owns (pixel q, oa) ----
    const int q   = t >> 8;
    const int oa  = t & 255;
    float* route_q = (float*)(lds + q * 4608);            // [32][36]
    float* logit_q = (float*)(lds + 9216 + q * 4608);     // [32][36]

    const float cb = conv_b[oa];
    float rowsum = 0.f;
    #pragma unroll
    for (int i = 0; i < 32; ++i) { v[i] += cb; rowsum += v[i]; }

    const int o_t = oa >> 3, a_t = t & 7;
    const float bias_v = biases[oa];
    float actv = 0.f;

    #pragma unroll
    for (int it = 0; it < 3; ++it) {
        float pre;
        if (it == 0) {
            pre = fmaf(rowsum, 1.f / 33.f, bias_v);
        } else {
            pre = bias_v;
            const float* rrow = route_q + o_t * 36;
            #pragma unroll
            for (int c = 0; c < 8; ++c) {
                const f32x4 rv = *(const f32x4*)(rrow + c * 4);
                pre = fmaf(v[c * 4 + 0], rv[0], pre);
                pre = fmaf(v[c * 4 + 1], rv[1], pre);
                pre = fmaf(v[c * 4 + 2], rv[2], pre);
                pre = fmaf(v[c * 4 + 3], rv[3], pre);
            }
        }

        // squash (8-atom DPP group); fast rsq/rcp
        const float ns = sum8(pre * pre);
        actv = pre * ns * __builtin_amdgcn_rsqf(ns) * __builtin_amdgcn_rcpf(1.f + ns);

        if (it < 2) {
            float dsum[32];
            #pragma unroll
            for (int i = 0; i < 32; ++i)
                dsum[i] = sum8(v[i] * actv);
            if (a_t == 0) {
                float* lrow = logit_q + o_t * 36;
                #pragma unroll
                for (int c = 0; c < 8; ++c) {
                    f32x4 cur = (it == 0) ? (f32x4){0.f, 0.f, 0.f, 0.f}
                                          : *(const f32x4*)(lrow + c * 4);
                    cur[0] += dsum[c * 4 + 0];
                    cur[1] += dsum[c * 4 + 1];
                    cur[2] += dsum[c * 4 + 2];
                    cur[3] += dsum[c * 4 + 3];
                    *(f32x4*)(lrow + c * 4) = cur;
                }
            }
            __syncthreads();

            // leaky softmax over o for row i = o_t (8 sub-lanes x 4 o's)
            const int r = o_t, sub = a_t;
            float e0 = logit_q[(sub * 4 + 0) * 36 + r];
            float e1 = logit_q[(sub * 4 + 1) * 36 + r];
            float e2 = logit_q[(sub * 4 + 2) * 36 + r];
            float e3 = logit_q[(sub * 4 + 3) * 36 + r];
            float mx = fmaxf(fmaxf(e0, e1), fmaxf(e2, e3));
            mx = max8(fmaxf(mx, 0.f));                // include leak logit 0
            e0 = __expf(e0 - mx); e1 = __expf(e1 - mx);
            e2 = __expf(e2 - mx); e3 = __expf(e3 - mx);
            const float ssum = sum8(e0 + e1 + e2 + e3) + __expf(-mx);
            const float inv = __builtin_amdgcn_rcpf(ssum);
            route_q[(sub * 4 + 0) * 36 + r] = e0 * inv;
            route_q[(sub * 4 + 1) * 36 + r] = e1 * inv;
            route_q[(sub * 4 + 2) * 36 + r] = e2 * inv;
            route_q[(sub * 4 + 3) * 36 + r] = e3 * inv;
            __syncthreads();
        }
    }

    // out[b][o][h][w][a]
    const int pix = (h << 5) + w0 + q;
    out[(((size_t)(((b << 5) + o_t) << 10) + pix) << 3) + a_t] = actv;
}

extern "C" void kernel_launch(void* const* d_in, const int* in_sizes, int n_in,
                              void* d_out, int out_size, void* d_ws, size_t ws_size,
                              hipStream_t stream) {
    const float* x      = (const float*)d_in[0];
    const float* conv_w = (const float*)d_in[1];
    const float* conv_b = (const float*)d_in[2];
    const float* biases = (const float*)d_in[3];
    unsigned short* wp = (unsigned short*)d_ws;                     // 114,688 B
    unsigned short* xt = (unsigned short*)((char*)d_ws + 131072);   // 4 MB
    prep_w<<<dim3(224), dim3(256), 0, stream>>>(conv_w, wp);
    prep_x<<<dim3(256), dim3(256), 0, stream>>>(x, xt);
    capsule_mfma2<<<dim3(4096), dim3(512), 0, stream>>>(xt, wp, conv_b, biases, (float*)d_out);
}

// Round 8
// 81.298 us; speedup vs baseline: 3.3124x; 1.0465x over previous
//
#include <hip/hip_runtime.h>
#include <math.h>

// ConvCapsule R8 = R7 minus 4 unnecessary __syncthreads().
// The vtr transpose buffer is PER-WAVE private: intra-wave LDS ordering is
// guaranteed by in-order DS issue + compiler lgkmcnt -- no block barrier
// needed. Removing them also de-lockstops the 8 waves (less skew at the
// real barriers). Everything else identical to R7 (85us, VGPR=60, no spill).

using short8 = __attribute__((ext_vector_type(8))) short;
using f32x4  = __attribute__((ext_vector_type(4))) float;

__device__ __forceinline__ unsigned short f2bf(float f) {
    unsigned u = __float_as_uint(f);
    return (unsigned short)((u + 0x7fffu + ((u >> 16) & 1u)) >> 16);  // RNE
}

template<int CTRL>
__device__ __forceinline__ float dpp_movf(float x) {
    return __int_as_float(__builtin_amdgcn_update_dpp(
        0, __float_as_int(x), CTRL, 0xF, 0xF, true));
}
__device__ __forceinline__ float sum8(float x) {
    x += dpp_movf<0xB1>(x);    // xor1
    x += dpp_movf<0x4E>(x);    // xor2
    x += dpp_movf<0x141>(x);   // xor4 (row_half_mirror)
    return x;
}
__device__ __forceinline__ float max8(float x) {
    x = fmaxf(x, dpp_movf<0xB1>(x));
    x = fmaxf(x, dpp_movf<0x4E>(x));
    x = fmaxf(x, dpp_movf<0x141>(x));
    return x;
}

// ---------- prep 1: W -> bf16, [s(7)][g(4)][oa(256)][j(8)], k = s*32+g*8+j ----------
__global__ __launch_bounds__(256)
void prep_w(const float* __restrict__ cw, unsigned short* __restrict__ wp) {
    const int idx = blockIdx.x * 256 + threadIdx.x;   // 57344 total
    const int j  = idx & 7;
    const int oa = (idx >> 3) & 255;
    const int g  = (idx >> 11) & 3;
    const int s  = idx >> 13;
    const int k  = s * 32 + g * 8 + j;
    wp[idx] = (k < 200) ? f2bf(cw[k * 256 + oa]) : (unsigned short)0;
}

// ---------- prep 2: x -> bf16 transposed [b][y][x][i*8+ci] ----------
__global__ __launch_bounds__(256)
void prep_x(const float* __restrict__ x, unsigned short* __restrict__ xt) {
    __shared__ unsigned short tile[32 * 256];         // [xx][plane]
    const int t = threadIdx.x;                        // plane = i*8+ci
    const int b = blockIdx.x >> 5, y = blockIdx.x & 31;
    const float* src = x + (((size_t)((b << 8) + t)) << 10) + (y << 5);
    #pragma unroll
    for (int c = 0; c < 8; ++c) {
        float4 v = *(const float4*)(src + c * 4);
        tile[(c * 4 + 0) * 256 + t] = f2bf(v.x);
        tile[(c * 4 + 1) * 256 + t] = f2bf(v.y);
        tile[(c * 4 + 2) * 256 + t] = f2bf(v.z);
        tile[(c * 4 + 3) * 256 + t] = f2bf(v.w);
    }
    __syncthreads();
    unsigned short* dst = xt + ((size_t)blockIdx.x << 13);
    #pragma unroll
    for (int c = 0; c < 4; ++c) {
        const int chunk = t + c * 256;
        *(short8*)(dst + chunk * 8) = *(const short8*)(&tile[chunk * 8]);
    }
}

// ---------- main fused kernel: 2 pixels / 512 threads / 8 waves ----------
__global__ __launch_bounds__(512, 4)
void capsule_mfma2(const unsigned short* __restrict__ xt,
                   const unsigned short* __restrict__ wp,
                   const float* __restrict__ conv_b,
                   const float* __restrict__ biases,
                   float* __restrict__ out)
{
    // Overlaid LDS phases (40960 B):
    //   A: patch [32 i][31 pos slots][8 ci] bf16, row stride 496 B (15872 B)
    //   B: vtr per-wave float[64][20], chunk-rotated (8 x 5120 = 40960 B)
    //   C: route_T[q] @ q*4608 ; logits_T[q] @ 9216 + q*4608  (18432 B)
    __shared__ __align__(16) char lds[40960];

    const int t   = threadIdx.x;
    const int blk = blockIdx.x;           // 4096
    const int b   = blk >> 9;
    const int rem = blk & 511;
    const int h   = rem >> 4;
    const int w0  = (rem & 15) << 1;      // pixels w0, w0+1

    // ---- stage patch: 30 pos x 32 i units, 16B each ----
    for (int u = t; u < 960; u += 512) {
        const int i = u & 31, pos = u >> 5;     // pos in [0,30)
        const int ky = pos / 6, xl = pos - ky * 6;
        const int y = h + ky - 2, xx = w0 + xl - 2;
        short8 v = {0, 0, 0, 0, 0, 0, 0, 0};
        if ((unsigned)y < 32u && (unsigned)xx < 32u)
            v = *(const short8*)(xt + (((size_t)(((b << 5) + y) << 5) + xx) << 8) + i * 8);
        *(short8*)(lds + i * 496 + pos * 16) = v;
    }

    const int l  = t & 63, wv = t >> 6;   // 8 waves
    const int lm = l & 15, lg = l >> 4;
    const int qw = wv >> 2;               // wave's pixel (conv phase)

    // hoist per-thread routing constants (global loads overlap conv/transpose)
    const int oa  = t & 255;
    const float cb     = conv_b[oa];
    const float bias_v = biases[oa];

    // conv: M=oa (A=W, wave owns 64 oa), N=i (B=patch), K=224
    f32x4 acc[4][2];
    #pragma unroll
    for (int mt = 0; mt < 4; ++mt)
        #pragma unroll
        for (int ti = 0; ti < 2; ++ti)
            acc[mt][ti] = (f32x4){0.f, 0.f, 0.f, 0.f};

    __syncthreads();   // patch ready

    const unsigned short* wbase = wp + lg * 2048 + ((((wv & 3) << 6) + lm) << 3);

    #pragma unroll
    for (int s = 0; s < 7; ++s) {
        short8 a[4];
        #pragma unroll
        for (int mt = 0; mt < 4; ++mt)
            a[mt] = *(const short8*)(wbase + s * 8192 + mt * 128);
        const int kt = s * 4 + lg;        // tap; k = s*32+lg*8+j
        int pos = 0;
        if (kt <= 24) { const int ky = kt / 5; pos = ky * 6 + (kt - ky * 5); }
        // kt>24: W slice is zero -> patch junk contributes 0
        const char* bb = lds + (pos + qw) * 16;
        const short8 b0 = *(const short8*)(bb + lm * 496);
        const short8 b1 = *(const short8*)(bb + (16 + lm) * 496);
        #pragma unroll
        for (int mt = 0; mt < 4; ++mt) {
            acc[mt][0] = __builtin_amdgcn_mfma_f32_16x16x32_bf16(a[mt], b0, acc[mt][0], 0, 0, 0);
            acc[mt][1] = __builtin_amdgcn_mfma_f32_16x16x32_bf16(a[mt], b1, acc[mt][1], 0, 0, 0);
        }
    }

    __syncthreads();   // all patch reads done; lds reusable for vtr

    // ---- transpose via per-wave vtr (chunk-rotated): thread t -> vote row ----
    // vtr is PER-WAVE PRIVATE: no __syncthreads needed, intra-wave DS ordering
    // (compiler lgkmcnt) is sufficient. C layout: lane (lm,lg) reg r of
    // acc[mt][ti] = votes[oa_l=mt*16+lg*4+r][i=ti*16+lm]
    float v[32];
    float* vtr = (float*)lds + wv * 1280;             // [64][20]
    #pragma unroll
    for (int ti = 0; ti < 2; ++ti) {
        #pragma unroll
        for (int mt = 0; mt < 4; ++mt)
            #pragma unroll
            for (int r = 0; r < 4; ++r) {
                const int row = mt * 16 + (lg << 2) + r;
                vtr[row * 20 + ((((lm >> 2) + (row >> 3)) & 3) << 2) + (lm & 3)] =
                    acc[mt][ti][r];
            }
        #pragma unroll
        for (int c = 0; c < 4; ++c) {
            const f32x4 vv = *(const f32x4*)(vtr + l * 20 + (((c + (l >> 3)) & 3) << 2));
            v[ti * 16 + c * 4 + 0] = vv[0];
            v[ti * 16 + c * 4 + 1] = vv[1];
            v[ti * 16 + c * 4 + 2] = vv[2];
            v[ti * 16 + c * 4 + 3] = vv[3];
        }
    }

    // ---- routing: thread t owns (pixel q, oa) ----
    const int q   = t >> 8;
    float* route_q = (float*)(lds + q * 4608);            // [32][36]
    float* logit_q = (float*)(lds + 9216 + q * 4608);     // [32][36]

    float rowsum = 0.f;
    #pragma unroll
    for (int i = 0; i < 32; ++i) { v[i] += cb; rowsum += v[i]; }

    const int o_t = oa >> 3, a_t = t & 7;
    float actv = 0.f;

    #pragma unroll
    for (int it = 0; it < 3; ++it) {
        float pre;
        if (it == 0) {
            pre = fmaf(rowsum, 1.f / 33.f, bias_v);
        } else {
            pre = bias_v;
            const float* rrow = route_q + o_t * 36;
            #pragma unroll
            for (int c = 0; c < 8; ++c) {
                const f32x4 rv = *(const f32x4*)(rrow + c * 4);
                pre = fmaf(v[c * 4 + 0], rv[0], pre);
                pre = fmaf(v[c * 4 + 1], rv[1], pre);
                pre = fmaf(v[c * 4 + 2], rv[2], pre);
                pre = fmaf(v[c * 4 + 3], rv[3], pre);
            }
        }

        // squash (8-atom DPP group); fast rsq/rcp
        const float ns = sum8(pre * pre);
        actv = pre * ns * __builtin_amdgcn_rsqf(ns) * __builtin_amdgcn_rcpf(1.f + ns);

        if (it < 2) {
            float dsum[32];
            #pragma unroll
            for (int i = 0; i < 32; ++i)
                dsum[i] = sum8(v[i] * actv);
            if (a_t == 0) {
                float* lrow = logit_q + o_t * 36;
                #pragma unroll
                for (int c = 0; c < 8; ++c) {
                    f32x4 cur = (it == 0) ? (f32x4){0.f, 0.f, 0.f, 0.f}
                                          : *(const f32x4*)(lrow + c * 4);
                    cur[0] += dsum[c * 4 + 0];
                    cur[1] += dsum[c * 4 + 1];
                    cur[2] += dsum[c * 4 + 2];
                    cur[3] += dsum[c * 4 + 3];
                    *(f32x4*)(lrow + c * 4) = cur;
                }
            }
            __syncthreads();

            // leaky softmax over o for row i = o_t (8 sub-lanes x 4 o's)
            const int r = o_t, sub = a_t;
            float e0 = logit_q[(sub * 4 + 0) * 36 + r];
            float e1 = logit_q[(sub * 4 + 1) * 36 + r];
            float e2 = logit_q[(sub * 4 + 2) * 36 + r];
            float e3 = logit_q[(sub * 4 + 3) * 36 + r];
            float mx = fmaxf(fmaxf(e0, e1), fmaxf(e2, e3));
            mx = max8(fmaxf(mx, 0.f));                // include leak logit 0
            e0 = __expf(e0 - mx); e1 = __expf(e1 - mx);
            e2 = __expf(e2 - mx); e3 = __expf(e3 - mx);
            const float ssum = sum8(e0 + e1 + e2 + e3) + __expf(-mx);
            const float inv = __builtin_amdgcn_rcpf(ssum);
            route_q[(sub * 4 + 0) * 36 + r] = e0 * inv;
            route_q[(sub * 4 + 1) * 36 + r] = e1 * inv;
            route_q[(sub * 4 + 2) * 36 + r] = e2 * inv;
            route_q[(sub * 4 + 3) * 36 + r] = e3 * inv;
            __syncthreads();
        }
    }

    // out[b][o][h][w][a]
    const int pix = (h << 5) + w0 + q;
    out[(((size_t)(((b << 5) + o_t) << 10) + pix) << 3) + a_t] = actv;
}

extern "C" void kernel_launch(void* const* d_in, const int* in_sizes, int n_in,
                              void* d_out, int out_size, void* d_ws, size_t ws_size,
                              hipStream_t stream) {
    const float* x      = (const float*)d_in[0];
    const float* conv_w = (const float*)d_in[1];
    const float* conv_b = (const float*)d_in[2];
    const float* biases = (const float*)d_in[3];
    unsigned short* wp = (unsigned short*)d_ws;                     // 114,688 B
    unsigned short* xt = (unsigned short*)((char*)d_ws + 131072);   // 4 MB
    prep_w<<<dim3(224), dim3(256), 0, stream>>>(conv_w, wp);
    prep_x<<<dim3(256), dim3(256), 0, stream>>>(x, xt);
    capsule_mfma2<<<dim3(4096), dim3(512), 0, stream>>>(xt, wp, conv_b, biases, (float*)d_out);
}

// Round 9
// 69.395 us; speedup vs baseline: 3.8805x; 1.1715x over previous
//
#include <hip/hip_runtime.h>
#include <math.h>

// ConvCapsule R9: xor-slot routing layout.
// Thread owns (pixel q, capsule o, i-group ig): v[di][j] = votes[i=ig*4+di][a=ig^j].
// - logit update: 32 local FMAs (was 32x sum8 DPP chains)
// - preact: 32 FMAs + 14-op butterfly reduce-transpose (DPP xor1/xor2 + ds_swizzle xor4)
// - act allgather: 7 ops, slot order matches v's xor slots
// - vtr stride 20: transpose-write offsets are immediates; 2-way conflicts (free)
// Also fixes R8's latent race: barrier between transpose reads and routing writes.

using short8 = __attribute__((ext_vector_type(8))) short;
using f32x4  = __attribute__((ext_vector_type(4))) float;

__device__ __forceinline__ unsigned short f2bf(float f) {
    unsigned u = __float_as_uint(f);
    return (unsigned short)((u + 0x7fffu + ((u >> 16) & 1u)) >> 16);  // RNE
}

template<int CTRL>
__device__ __forceinline__ float dpp_movf(float x) {
    return __int_as_float(__builtin_amdgcn_update_dpp(
        0, __float_as_int(x), CTRL, 0xF, 0xF, true));
}
__device__ __forceinline__ float swz_xor4(float x) {   // lane ^= 4 (LDS pipe)
    return __int_as_float(__builtin_amdgcn_ds_swizzle(__float_as_int(x), 0x101F));
}
__device__ __forceinline__ float sum8(float x) {       // plain 8-lane reduce
    x += dpp_movf<0xB1>(x);
    x += dpp_movf<0x4E>(x);
    x += dpp_movf<0x141>(x);
    return x;
}
__device__ __forceinline__ float max8(float x) {
    x = fmaxf(x, dpp_movf<0xB1>(x));
    x = fmaxf(x, dpp_movf<0x4E>(x));
    x = fmaxf(x, dpp_movf<0x141>(x));
    return x;
}
// butterfly reduce-transpose over the 8-lane o-group:
// input p[j] holds partial for a = ig^j; returns full sum for a = ig.
__device__ __forceinline__ float reduce_xpose8(float p[8]) {
    p[0] += dpp_movf<0xB1>(p[1]);   // stage xor1: keep j in {0,2,4,6}
    p[2] += dpp_movf<0xB1>(p[3]);
    p[4] += dpp_movf<0xB1>(p[5]);
    p[6] += dpp_movf<0xB1>(p[7]);
    p[0] += dpp_movf<0x4E>(p[2]);   // stage xor2: keep {0,4}
    p[4] += dpp_movf<0x4E>(p[6]);
    p[0] += swz_xor4(p[4]);         // stage xor4
    return p[0];
}

// ---------- prep 1: W -> bf16, [s(7)][g(4)][oa(256)][j(8)], k = s*32+g*8+j ----------
__global__ __launch_bounds__(256)
void prep_w(const float* __restrict__ cw, unsigned short* __restrict__ wp) {
    const int idx = blockIdx.x * 256 + threadIdx.x;   // 57344 total
    const int j  = idx & 7;
    const int oa = (idx >> 3) & 255;
    const int g  = (idx >> 11) & 3;
    const int s  = idx >> 13;
    const int k  = s * 32 + g * 8 + j;
    wp[idx] = (k < 200) ? f2bf(cw[k * 256 + oa]) : (unsigned short)0;
}

// ---------- prep 2: x -> bf16 transposed [b][y][x][i*8+ci] ----------
__global__ __launch_bounds__(256)
void prep_x(const float* __restrict__ x, unsigned short* __restrict__ xt) {
    __shared__ unsigned short tile[32 * 256];         // [xx][plane]
    const int t = threadIdx.x;                        // plane = i*8+ci
    const int b = blockIdx.x >> 5, y = blockIdx.x & 31;
    const float* src = x + (((size_t)((b << 8) + t)) << 10) + (y << 5);
    #pragma unroll
    for (int c = 0; c < 8; ++c) {
        float4 v = *(const float4*)(src + c * 4);
        tile[(c * 4 + 0) * 256 + t] = f2bf(v.x);
        tile[(c * 4 + 1) * 256 + t] = f2bf(v.y);
        tile[(c * 4 + 2) * 256 + t] = f2bf(v.z);
        tile[(c * 4 + 3) * 256 + t] = f2bf(v.w);
    }
    __syncthreads();
    unsigned short* dst = xt + ((size_t)blockIdx.x << 13);
    #pragma unroll
    for (int c = 0; c < 4; ++c) {
        const int chunk = t + c * 256;
        *(short8*)(dst + chunk * 8) = *(const short8*)(&tile[chunk * 8]);
    }
}

// ---------- main fused kernel: 2 pixels / 512 threads / 8 waves ----------
__global__ __launch_bounds__(512, 4)
void capsule_mfma2(const unsigned short* __restrict__ xt,
                   const unsigned short* __restrict__ wp,
                   const float* __restrict__ conv_b,
                   const float* __restrict__ biases,
                   float* __restrict__ out)
{
    // Overlaid LDS (40960 B, 4 blocks/CU):
    //   A: patch [32 i][31 pos][8 ci] bf16, row 496 B       (15872)
    //   B: vtr per-wave [64 oa_l][20 w] f32 @ wv*5120       (40960)
    //   C: logits[q] @ q*4608 ; route[q] @ 9216 + q*4608    (18432)
    __shared__ __align__(16) char lds[40960];

    const int t   = threadIdx.x;
    const int blk = blockIdx.x;           // 4096
    const int b   = blk >> 9;
    const int rem = blk & 511;
    const int h   = rem >> 4;
    const int w0  = (rem & 15) << 1;      // pixels w0, w0+1

    // ---- stage patch: 30 pos x 32 i units, 16B each ----
    for (int u = t; u < 960; u += 512) {
        const int i = u & 31, pos = u >> 5;
        const int ky = pos / 6, xl = pos - ky * 6;
        const int y = h + ky - 2, xx = w0 + xl - 2;
        short8 vv = {0, 0, 0, 0, 0, 0, 0, 0};
        if ((unsigned)y < 32u && (unsigned)xx < 32u)
            vv = *(const short8*)(xt + (((size_t)(((b << 5) + y) << 5) + xx) << 8) + i * 8);
        *(short8*)(lds + i * 496 + pos * 16) = vv;
    }

    const int l  = t & 63, wv = t >> 6;   // 8 waves
    const int lm = l & 15, lg = l >> 4;   // conv C-layout coords
    const int o_l = l >> 3, ig = l & 7;   // routing coords
    const int o  = ((wv & 3) << 3) + o_l; // capsule 0..31
    const int q  = wv >> 2;               // pixel (conv & routing agree)

    // hoisted scalars (conv_b[o*8+ig] == conv_b[t&255])
    const float cb_own   = conv_b[t & 255];
    const float bias_own = biases[t & 255];

    // conv: M=oa (A=W, wave owns 64 oa), N=i (B=patch), K=224
    f32x4 acc[4][2];
    #pragma unroll
    for (int mt = 0; mt < 4; ++mt)
        #pragma unroll
        for (int ti = 0; ti < 2; ++ti)
            acc[mt][ti] = (f32x4){0.f, 0.f, 0.f, 0.f};

    __syncthreads();   // patch ready

    const unsigned short* wbase = wp + lg * 2048 + ((((wv & 3) << 6) + lm) << 3);

    #pragma unroll
    for (int s = 0; s < 7; ++s) {
        short8 a[4];
        #pragma unroll
        for (int mt = 0; mt < 4; ++mt)
            a[mt] = *(const short8*)(wbase + s * 8192 + mt * 128);
        const int kt = s * 4 + lg;
        int pos = 0;
        if (kt <= 24) { const int ky = kt / 5; pos = ky * 6 + (kt - ky * 5); }
        const char* bb = lds + (pos + q) * 16;
        const short8 b0 = *(const short8*)(bb + lm * 496);
        const short8 b1 = *(const short8*)(bb + (16 + lm) * 496);
        #pragma unroll
        for (int mt = 0; mt < 4; ++mt) {
            acc[mt][0] = __builtin_amdgcn_mfma_f32_16x16x32_bf16(a[mt], b0, acc[mt][0], 0, 0, 0);
            acc[mt][1] = __builtin_amdgcn_mfma_f32_16x16x32_bf16(a[mt], b1, acc[mt][1], 0, 0, 0);
        }
    }

    __syncthreads();   // patch reads done; lds reusable for vtr

    // ---- per-wave transpose to xor-slot registers ----
    // vtr row oa_l = o_l*8 + a (stride 20 words); write offsets are immediates.
    // C layout: lane (lm,lg) reg r of acc[mt][ro] = votes[oa_l=mt*16+lg*4+r][i=ro*16+lm]
    float v[4][8];                        // v[di][j]: i = ig*4+di, a = ig^j
    char* vtrb = lds + wv * 5120;
    const int wbyte = lg * 320 + lm * 4;
    const int rbase = o_l * 640 + (ig & 3) * 16;
    #pragma unroll
    for (int ro = 0; ro < 2; ++ro) {
        #pragma unroll
        for (int mt = 0; mt < 4; ++mt)
            #pragma unroll
            for (int r = 0; r < 4; ++r)
                *(float*)(vtrb + wbyte + mt * 1280 + r * 80) = acc[mt][ro][r];
        if ((ig >> 2) == ro) {            // this lane's 4 i's live in round ro
            #pragma unroll
            for (int j = 0; j < 8; ++j) {
                const int a = ig ^ j;
                const f32x4 r4 = *(const f32x4*)(vtrb + rbase + a * 80);
                v[0][j] = r4[0]; v[1][j] = r4[1]; v[2][j] = r4[2]; v[3][j] = r4[3];
            }
        }
    }
    __syncthreads();   // ALL vtr reads done before routing writes reuse [0,18432)

    float* logits_q = (float*)(lds + q * 4608);          // [32 i][36] f32
    float* route_q  = (float*)(lds + 9216 + q * 4608);   // [32 i][36] f32
    const int rw_byte = ig * 576 + o * 4;                // [i=ig*4+di][o], +di*144
    const int sm_byte = o * 144 + (ig << 4);             // [i=o][4ig..+4] b128

    float lacc[4] = {0.f, 0.f, 0.f, 0.f};
    float actv = 0.f;

    #pragma unroll
    for (int it = 0; it < 3; ++it) {
        // ---- preact: pre(o, a=ig) ----
        float pre;
        if (it == 0) {
            float p[8];
            #pragma unroll
            for (int j = 0; j < 8; ++j)
                p[j] = (v[0][j] + v[1][j]) + (v[2][j] + v[3][j]);
            const float R = reduce_xpose8(p);            // sum_i votes[i][a=ig]
            pre = fmaf(fmaf(cb_own, 32.f, R), 1.f / 33.f, bias_own);
        } else {
            float r4[4];
            #pragma unroll
            for (int di = 0; di < 4; ++di)
                r4[di] = *(const float*)((char*)route_q + rw_byte + di * 144);
            float p[8];
            #pragma unroll
            for (int j = 0; j < 8; ++j) {
                float s = v[0][j] * r4[0];
                s = fmaf(v[1][j], r4[1], s);
                s = fmaf(v[2][j], r4[2], s);
                s = fmaf(v[3][j], r4[3], s);
                p[j] = s;
            }
            const float S_o = sum8((r4[0] + r4[1]) + (r4[2] + r4[3]));
            const float P = reduce_xpose8(p);
            pre = fmaf(cb_own, S_o, P) + bias_own;
        }

        // ---- squash over atoms (o-group lanes) ----
        const float ns = sum8(pre * pre);
        actv = pre * ns * __builtin_amdgcn_rsqf(ns) * __builtin_amdgcn_rcpf(1.f + ns);

        if (it < 2) {
            // ---- act allgather in xor-slot order: ag[j] = act[ig^j] ----
            float ag[8];
            ag[0] = actv;
            ag[4] = swz_xor4(ag[0]);
            ag[2] = dpp_movf<0x4E>(ag[0]);
            ag[6] = dpp_movf<0x4E>(ag[4]);
            ag[1] = dpp_movf<0xB1>(ag[0]);
            ag[3] = dpp_movf<0xB1>(ag[2]);
            ag[5] = dpp_movf<0xB1>(ag[4]);
            ag[7] = dpp_movf<0xB1>(ag[6]);
            const float cbact = sum8(cb_own * actv);     // sum_a cb[a]*act[a]

            // ---- logit update: 32 local FMAs; accumulate in registers ----
            #pragma unroll
            for (int di = 0; di < 4; ++di) {
                float d = cbact;
                #pragma unroll
                for (int j = 0; j < 8; ++j)
                    d = fmaf(v[di][j], ag[j], d);
                lacc[di] += d;
                *(float*)((char*)logits_q + rw_byte + di * 144) = lacc[di];
            }
            __syncthreads();

            // ---- leaky softmax over o for row i = o; cols ig*4..+4 ----
            f32x4 e = *(const f32x4*)((char*)logits_q + sm_byte);
            float mx = fmaxf(fmaxf(e[0], e[1]), fmaxf(e[2], e[3]));
            mx = max8(fmaxf(mx, 0.f));                   // include leak logit 0
            e[0] = __expf(e[0] - mx); e[1] = __expf(e[1] - mx);
            e[2] = __expf(e[2] - mx); e[3] = __expf(e[3] - mx);
            const float ssum = sum8((e[0] + e[1]) + (e[2] + e[3])) + __expf(-mx);
            const float inv = __builtin_amdgcn_rcpf(ssum);
            e[0] *= inv; e[1] *= inv; e[2] *= inv; e[3] *= inv;
            *(f32x4*)((char*)route_q + sm_byte) = e;
            __syncthreads();
        }
    }

    // out[b][o][h][w][a]: a = ig
    const int pix = (h << 5) + w0 + q;
    out[(((size_t)(((b << 5) + o) << 10) + pix) << 3) + ig] = actv;
}

extern "C" void kernel_launch(void* const* d_in, const int* in_sizes, int n_in,
                              void* d_out, int out_size, void* d_ws, size_t ws_size,
                              hipStream_t stream) {
    const float* x      = (const float*)d_in[0];
    const float* conv_w = (const float*)d_in[1];
    const float* conv_b = (const float*)d_in[2];
    const float* biases = (const float*)d_in[3];
    unsigned short* wp = (unsigned short*)d_ws;                     // 114,688 B
    unsigned short* xt = (unsigned short*)((char*)d_ws + 131072);   // 4 MB
    prep_w<<<dim3(224), dim3(256), 0, stream>>>(conv_w, wp);
    prep_x<<<dim3(256), dim3(256), 0, stream>>>(x, xt);
    capsule_mfma2<<<dim3(4096), dim3(512), 0, stream>>>(xt, wp, conv_b, biases, (float*)d_out);
}

// Round 10
// 68.234 us; speedup vs baseline: 3.9465x; 1.0170x over previous
//
#include <hip/hip_runtime.h>
#include <math.h>

// ConvCapsule R10 = R9 + {6-barrier schedule, dedicated vtr region, patch XOR
// swizzle, vtr chunk rotation, W s=0 prefetch, setprio on MFMA}.
// LDS map (38912 B, 4 blocks/CU = 32 waves = occupancy cap):
//   patch   [0,16384): [32 i][32 slots][16B], slot = pos ^ (i&15)
//   routing [0,18432): logits q*4608 ; route 9216+q*4608  (after pre-logit barrier)
//   vtr     [18432,38912): per-wave [32 rows][80 B], chunk-rotated

using short8 = __attribute__((ext_vector_type(8))) short;
using f32x4  = __attribute__((ext_vector_type(4))) float;

__device__ __forceinline__ unsigned short f2bf(float f) {
    unsigned u = __float_as_uint(f);
    return (unsigned short)((u + 0x7fffu + ((u >> 16) & 1u)) >> 16);  // RNE
}

template<int CTRL>
__device__ __forceinline__ float dpp_movf(float x) {
    return __int_as_float(__builtin_amdgcn_update_dpp(
        0, __float_as_int(x), CTRL, 0xF, 0xF, true));
}
__device__ __forceinline__ float swz_xor4(float x) {   // lane ^= 4
    return __int_as_float(__builtin_amdgcn_ds_swizzle(__float_as_int(x), 0x101F));
}
__device__ __forceinline__ float sum8(float x) {
    x += dpp_movf<0xB1>(x);
    x += dpp_movf<0x4E>(x);
    x += dpp_movf<0x141>(x);
    return x;
}
__device__ __forceinline__ float max8(float x) {
    x = fmaxf(x, dpp_movf<0xB1>(x));
    x = fmaxf(x, dpp_movf<0x4E>(x));
    x = fmaxf(x, dpp_movf<0x141>(x));
    return x;
}
// butterfly reduce-transpose over 8-lane group: p[j] holds partial for a=ig^j;
// returns full sum for a=ig.
__device__ __forceinline__ float reduce_xpose8(float p[8]) {
    p[0] += dpp_movf<0xB1>(p[1]);
    p[2] += dpp_movf<0xB1>(p[3]);
    p[4] += dpp_movf<0xB1>(p[5]);
    p[6] += dpp_movf<0xB1>(p[7]);
    p[0] += dpp_movf<0x4E>(p[2]);
    p[4] += dpp_movf<0x4E>(p[6]);
    p[0] += swz_xor4(p[4]);
    return p[0];
}

// ---------- prep 1: W -> bf16, [s(7)][g(4)][oa(256)][j(8)], k = s*32+g*8+j ----------
__global__ __launch_bounds__(256)
void prep_w(const float* __restrict__ cw, unsigned short* __restrict__ wp) {
    const int idx = blockIdx.x * 256 + threadIdx.x;   // 57344 total
    const int j  = idx & 7;
    const int oa = (idx >> 3) & 255;
    const int g  = (idx >> 11) & 3;
    const int s  = idx >> 13;
    const int k  = s * 32 + g * 8 + j;
    wp[idx] = (k < 200) ? f2bf(cw[k * 256 + oa]) : (unsigned short)0;
}

// ---------- prep 2: x -> bf16 transposed [b][y][x][i*8+ci] ----------
__global__ __launch_bounds__(256)
void prep_x(const float* __restrict__ x, unsigned short* __restrict__ xt) {
    __shared__ unsigned short tile[32 * 256];         // [xx][plane]
    const int t = threadIdx.x;                        // plane = i*8+ci
    const int b = blockIdx.x >> 5, y = blockIdx.x & 31;
    const float* src = x + (((size_t)((b << 8) + t)) << 10) + (y << 5);
    #pragma unroll
    for (int c = 0; c < 8; ++c) {
        float4 v = *(const float4*)(src + c * 4);
        tile[(c * 4 + 0) * 256 + t] = f2bf(v.x);
        tile[(c * 4 + 1) * 256 + t] = f2bf(v.y);
        tile[(c * 4 + 2) * 256 + t] = f2bf(v.z);
        tile[(c * 4 + 3) * 256 + t] = f2bf(v.w);
    }
    __syncthreads();
    unsigned short* dst = xt + ((size_t)blockIdx.x << 13);
    #pragma unroll
    for (int c = 0; c < 4; ++c) {
        const int chunk = t + c * 256;
        *(short8*)(dst + chunk * 8) = *(const short8*)(&tile[chunk * 8]);
    }
}

// ---------- main fused kernel: 2 pixels / 512 threads / 8 waves ----------
__global__ __launch_bounds__(512, 4)
void capsule_mfma2(const unsigned short* __restrict__ xt,
                   const unsigned short* __restrict__ wp,
                   const float* __restrict__ conv_b,
                   const float* __restrict__ biases,
                   float* __restrict__ out)
{
    __shared__ __align__(16) char lds[38912];

    const int t   = threadIdx.x;
    const int blk = blockIdx.x;           // 4096
    const int b   = blk >> 9;
    const int rem = blk & 511;
    const int h   = rem >> 4;
    const int w0  = (rem & 15) << 1;      // pixels w0, w0+1

    // ---- stage patch: slot XOR-swizzled, row stride 512B ----
    for (int u = t; u < 960; u += 512) {
        const int i = u & 31, pos = u >> 5;          // pos in [0,30)
        const int ky = pos / 6, xl = pos - ky * 6;
        const int y = h + ky - 2, xx = w0 + xl - 2;
        short8 vv = {0, 0, 0, 0, 0, 0, 0, 0};
        if ((unsigned)y < 32u && (unsigned)xx < 32u)
            vv = *(const short8*)(xt + (((size_t)(((b << 5) + y) << 5) + xx) << 8) + i * 8);
        *(short8*)(lds + i * 512 + ((pos ^ (i & 15)) << 4)) = vv;
    }

    const int l  = t & 63, wv = t >> 6;   // 8 waves
    const int lm = l & 15, lg = l >> 4;   // conv C-layout coords
    const int o_l = l >> 3, ig = l & 7;   // routing coords
    const int o  = ((wv & 3) << 3) + o_l; // capsule 0..31
    const int q  = wv >> 2;               // pixel

    const float cb_own   = conv_b[t & 255];
    const float bias_own = biases[t & 255];

    // W s=0 prefetch (hides L2 latency under the staging barrier)
    const unsigned short* wbase = wp + lg * 2048 + ((((wv & 3) << 6) + lm) << 3);
    short8 a0[4];
    #pragma unroll
    for (int mt = 0; mt < 4; ++mt)
        a0[mt] = *(const short8*)(wbase + mt * 128);

    f32x4 acc[4][2];
    #pragma unroll
    for (int mt = 0; mt < 4; ++mt)
        #pragma unroll
        for (int ti = 0; ti < 2; ++ti)
            acc[mt][ti] = (f32x4){0.f, 0.f, 0.f, 0.f};

    __syncthreads();   // B0: patch ready

    // conv: M=oa (A=W, wave owns 64 oa), N=i (B=patch), K=224
    #pragma unroll
    for (int s = 0; s < 7; ++s) {
        short8 a[4];
        #pragma unroll
        for (int mt = 0; mt < 4; ++mt)
            a[mt] = (s == 0) ? a0[mt]
                             : *(const short8*)(wbase + s * 8192 + mt * 128);
        const int kt = s * 4 + lg;
        int pos = 0;
        if (kt <= 24) { const int ky = kt / 5; pos = ky * 6 + (kt - ky * 5); }
        const int pr = pos + q;           // logical slot; phys = pr ^ (i&15)
        const short8 b0 = *(const short8*)(lds + lm * 512 + ((pr ^ lm) << 4));
        const short8 b1 = *(const short8*)(lds + (16 + lm) * 512 + ((pr ^ lm) << 4));
        __builtin_amdgcn_s_setprio(1);
        #pragma unroll
        for (int mt = 0; mt < 4; ++mt) {
            acc[mt][0] = __builtin_amdgcn_mfma_f32_16x16x32_bf16(a[mt], b0, acc[mt][0], 0, 0, 0);
            acc[mt][1] = __builtin_amdgcn_mfma_f32_16x16x32_bf16(a[mt], b1, acc[mt][1], 0, 0, 0);
        }
        __builtin_amdgcn_s_setprio(0);
    }

    // ---- per-wave transpose, 4 rounds (mh,ro); vtr region is dedicated ----
    // NO barrier: vtr disjoint from patch & routing; all traffic intra-wave.
    // write: row' = (mt&1)*16+4lg+r, chunk_phys = ((lm>>2)+(row'>>3))&3
    // read:  row' = 8(o_l&3)+(ig^j), chunk_phys = ((ig&3)+(o_l&3))&3
    float v[4][8];                        // v[di][j]: i = 4ig+di, a = ig^j
    char* vtrb = lds + 18432 + wv * 2560; // [32 rows][80 B]
    #pragma unroll
    for (int mh = 0; mh < 2; ++mh)
        #pragma unroll
        for (int ro = 0; ro < 2; ++ro) {
            #pragma unroll
            for (int m2 = 0; m2 < 2; ++m2)
                #pragma unroll
                for (int r = 0; r < 4; ++r) {
                    const int row = (m2 << 4) + (lg << 2) + r;
                    *(float*)(vtrb + row * 80 +
                              ((((lm >> 2) + (row >> 3)) & 3) << 4) + ((lm & 3) << 2)) =
                        acc[mh * 2 + m2][ro][r];
                }
            if ((ig >> 2) == ro && (o_l >> 2) == mh) {
                const int cph = (((ig & 3) + (o_l & 3)) & 3) << 4;
                #pragma unroll
                for (int j = 0; j < 8; ++j) {
                    const int row = ((o_l & 3) << 3) + (ig ^ j);
                    const f32x4 r4 = *(const f32x4*)(vtrb + row * 80 + cph);
                    v[0][j] = r4[0]; v[1][j] = r4[1]; v[2][j] = r4[2]; v[3][j] = r4[3];
                }
            }
        }

    float* logits_q = (float*)(lds + q * 4608);          // [32 i][36] f32
    float* route_q  = (float*)(lds + 9216 + q * 4608);   // [32 i][36] f32
    const int rw_byte = ig * 576 + o * 4;                // logits[i=4ig+di][o], +di*144
    const int sm_byte = o * 144 + (ig << 4);             // row i=o, cols 4ig.., b128

    float lacc[4] = {0.f, 0.f, 0.f, 0.f};
    float actv = 0.f;

    #pragma unroll
    for (int it = 0; it < 3; ++it) {
        // ---- preact: pre(o, a=ig) ----
        float pre;
        if (it == 0) {
            float p[8];
            #pragma unroll
            for (int j = 0; j < 8; ++j)
                p[j] = (v[0][j] + v[1][j]) + (v[2][j] + v[3][j]);
            const float R = reduce_xpose8(p);
            pre = fmaf(fmaf(cb_own, 32.f, R), 1.f / 33.f, bias_own);
        } else {
            float r4[4];
            #pragma unroll
            for (int di = 0; di < 4; ++di)
                r4[di] = *(const float*)((char*)route_q + rw_byte + di * 144);
            float p[8];
            #pragma unroll
            for (int j = 0; j < 8; ++j) {
                float s = v[0][j] * r4[0];
                s = fmaf(v[1][j], r4[1], s);
                s = fmaf(v[2][j], r4[2], s);
                s = fmaf(v[3][j], r4[3], s);
                p[j] = s;
            }
            const float S_o = sum8((r4[0] + r4[1]) + (r4[2] + r4[3]));
            const float P = reduce_xpose8(p);
            pre = fmaf(cb_own, S_o, P) + bias_own;
        }

        // ---- squash over atoms ----
        const float ns = sum8(pre * pre);
        actv = pre * ns * __builtin_amdgcn_rsqf(ns) * __builtin_amdgcn_rcpf(1.f + ns);

        if (it < 2) {
            // act allgather in xor-slot order
            float ag[8];
            ag[0] = actv;
            ag[4] = swz_xor4(ag[0]);
            ag[2] = dpp_movf<0x4E>(ag[0]);
            ag[6] = dpp_movf<0x4E>(ag[4]);
            ag[1] = dpp_movf<0xB1>(ag[0]);
            ag[3] = dpp_movf<0xB1>(ag[2]);
            ag[5] = dpp_movf<0xB1>(ag[4]);
            ag[7] = dpp_movf<0xB1>(ag[6]);
            const float cbact = sum8(cb_own * actv);

            // logit update in registers
            #pragma unroll
            for (int di = 0; di < 4; ++di) {
                float d = cbact;
                #pragma unroll
                for (int j = 0; j < 8; ++j)
                    d = fmaf(v[di][j], ag[j], d);
                lacc[di] += d;
            }

            // B1 (iter0 only): all conv patch reads done before logits reuse region
            if (it == 0) __syncthreads();

            #pragma unroll
            for (int di = 0; di < 4; ++di)
                *(float*)((char*)logits_q + rw_byte + di * 144) = lacc[di];
            __syncthreads();   // B2/B4

            // leaky softmax over o for row i = o
            f32x4 e = *(const f32x4*)((char*)logits_q + sm_byte);
            float mx = fmaxf(fmaxf(e[0], e[1]), fmaxf(e[2], e[3]));
            mx = max8(fmaxf(mx, 0.f));                   // include leak logit 0
            e[0] = __expf(e[0] - mx); e[1] = __expf(e[1] - mx);
            e[2] = __expf(e[2] - mx); e[3] = __expf(e[3] - mx);
            const float ssum = sum8((e[0] + e[1]) + (e[2] + e[3])) + __expf(-mx);
            const float inv = __builtin_amdgcn_rcpf(ssum);
            e[0] *= inv; e[1] *= inv; e[2] *= inv; e[3] *= inv;
            *(f32x4*)((char*)route_q + sm_byte) = e;
            __syncthreads();   // B3/B5
        }
    }

    // out[b][o][h][w][a]: a = ig
    const int pix = (h << 5) + w0 + q;
    out[(((size_t)(((b << 5) + o) << 10) + pix) << 3) + ig] = actv;
}

extern "C" void kernel_launch(void* const* d_in, const int* in_sizes, int n_in,
                              void* d_out, int out_size, void* d_ws, size_t ws_size,
                              hipStream_t stream) {
    const float* x      = (const float*)d_in[0];
    const float* conv_w = (const float*)d_in[1];
    const float* conv_b = (const float*)d_in[2];
    const float* biases = (const float*)d_in[3];
    unsigned short* wp = (unsigned short*)d_ws;                     // 114,688 B
    unsigned short* xt = (unsigned short*)((char*)d_ws + 131072);   // 4 MB
    prep_w<<<dim3(224), dim3(256), 0, stream>>>(conv_w, wp);
    prep_x<<<dim3(256), dim3(256), 0, stream>>>(x, xt);
    capsule_mfma2<<<dim3(4096), dim3(512), 0, stream>>>(xt, wp, conv_b, biases, (float*)d_out);
}

// Round 11
// 65.655 us; speedup vs baseline: 4.1015x; 1.0393x over previous
//
#include <hip/hip_runtime.h>
#include <math.h>

// ConvCapsule R11 = R10 + {routing LDS stride 37 words (kills 4/8-way bank
// conflicts in logits/route/softmax access), merged prep kernel (one launch)}.
// LDS map (39424 B, 4 blocks/CU = wave cap):
//   patch   [0,16384): [32 i][32 slots][16B], slot = pos ^ (i&15)   (conv phase)
//   routing [0,18944): logits q*4736 ; route 9472+q*4736 ([32][37] f32 each)
//   vtr     [18944,39424): per-wave [32 rows][80 B], chunk-rotated

using short8 = __attribute__((ext_vector_type(8))) short;
using f32x4  = __attribute__((ext_vector_type(4))) float;

__device__ __forceinline__ unsigned short f2bf(float f) {
    unsigned u = __float_as_uint(f);
    return (unsigned short)((u + 0x7fffu + ((u >> 16) & 1u)) >> 16);  // RNE
}

template<int CTRL>
__device__ __forceinline__ float dpp_movf(float x) {
    return __int_as_float(__builtin_amdgcn_update_dpp(
        0, __float_as_int(x), CTRL, 0xF, 0xF, true));
}
__device__ __forceinline__ float swz_xor4(float x) {   // lane ^= 4
    return __int_as_float(__builtin_amdgcn_ds_swizzle(__float_as_int(x), 0x101F));
}
__device__ __forceinline__ float sum8(float x) {
    x += dpp_movf<0xB1>(x);
    x += dpp_movf<0x4E>(x);
    x += dpp_movf<0x141>(x);
    return x;
}
__device__ __forceinline__ float max8(float x) {
    x = fmaxf(x, dpp_movf<0xB1>(x));
    x = fmaxf(x, dpp_movf<0x4E>(x));
    x = fmaxf(x, dpp_movf<0x141>(x));
    return x;
}
// butterfly reduce-transpose over 8-lane group: p[j] holds partial for a=ig^j;
// returns full sum for a=ig.
__device__ __forceinline__ float reduce_xpose8(float p[8]) {
    p[0] += dpp_movf<0xB1>(p[1]);
    p[2] += dpp_movf<0xB1>(p[3]);
    p[4] += dpp_movf<0xB1>(p[5]);
    p[6] += dpp_movf<0xB1>(p[7]);
    p[0] += dpp_movf<0x4E>(p[2]);
    p[4] += dpp_movf<0x4E>(p[6]);
    p[0] += swz_xor4(p[4]);
    return p[0];
}

// ---------- merged prep: blocks [0,224) -> W bf16 repack; [224,480) -> x transpose ----------
__global__ __launch_bounds__(256)
void prep(const float* __restrict__ cw, const float* __restrict__ x,
          unsigned short* __restrict__ wp, unsigned short* __restrict__ xt) {
    __shared__ unsigned short tile[32 * 256];
    const int t = threadIdx.x;
    if (blockIdx.x < 224) {
        // W -> bf16, [s(7)][g(4)][oa(256)][j(8)], k = s*32+g*8+j
        const int idx = blockIdx.x * 256 + t;         // 57344 total
        const int j  = idx & 7;
        const int oa = (idx >> 3) & 255;
        const int g  = (idx >> 11) & 3;
        const int s  = idx >> 13;
        const int k  = s * 32 + g * 8 + j;
        wp[idx] = (k < 200) ? f2bf(cw[k * 256 + oa]) : (unsigned short)0;
        return;
    }
    // x -> bf16 transposed [b][y][x][i*8+ci]
    const int bid = blockIdx.x - 224;                 // 256 blocks
    const int b = bid >> 5, y = bid & 31;
    const float* src = x + (((size_t)((b << 8) + t)) << 10) + (y << 5);
    #pragma unroll
    for (int c = 0; c < 8; ++c) {
        float4 v = *(const float4*)(src + c * 4);
        tile[(c * 4 + 0) * 256 + t] = f2bf(v.x);
        tile[(c * 4 + 1) * 256 + t] = f2bf(v.y);
        tile[(c * 4 + 2) * 256 + t] = f2bf(v.z);
        tile[(c * 4 + 3) * 256 + t] = f2bf(v.w);
    }
    __syncthreads();
    unsigned short* dst = xt + ((size_t)bid << 13);
    #pragma unroll
    for (int c = 0; c < 4; ++c) {
        const int chunk = t + c * 256;
        *(short8*)(dst + chunk * 8) = *(const short8*)(&tile[chunk * 8]);
    }
}

// ---------- main fused kernel: 2 pixels / 512 threads / 8 waves ----------
__global__ __launch_bounds__(512, 4)
void capsule_mfma2(const unsigned short* __restrict__ xt,
                   const unsigned short* __restrict__ wp,
                   const float* __restrict__ conv_b,
                   const float* __restrict__ biases,
                   float* __restrict__ out)
{
    __shared__ __align__(16) char lds[39424];

    const int t   = threadIdx.x;
    const int blk = blockIdx.x;           // 4096
    const int b   = blk >> 9;
    const int rem = blk & 511;
    const int h   = rem >> 4;
    const int w0  = (rem & 15) << 1;      // pixels w0, w0+1

    // ---- stage patch: slot XOR-swizzled, row stride 512B ----
    for (int u = t; u < 960; u += 512) {
        const int i = u & 31, pos = u >> 5;          // pos in [0,30)
        const int ky = pos / 6, xl = pos - ky * 6;
        const int y = h + ky - 2, xx = w0 + xl - 2;
        short8 vv = {0, 0, 0, 0, 0, 0, 0, 0};
        if ((unsigned)y < 32u && (unsigned)xx < 32u)
            vv = *(const short8*)(xt + (((size_t)(((b << 5) + y) << 5) + xx) << 8) + i * 8);
        *(short8*)(lds + i * 512 + ((pos ^ (i & 15)) << 4)) = vv;
    }

    const int l  = t & 63, wv = t >> 6;   // 8 waves
    const int lm = l & 15, lg = l >> 4;   // conv C-layout coords
    const int o_l = l >> 3, ig = l & 7;   // routing coords
    const int o  = ((wv & 3) << 3) + o_l; // capsule 0..31
    const int q  = wv >> 2;               // pixel

    const float cb_own   = conv_b[t & 255];
    const float bias_own = biases[t & 255];

    // W s=0 prefetch (hides L2 latency under the staging barrier)
    const unsigned short* wbase = wp + lg * 2048 + ((((wv & 3) << 6) + lm) << 3);
    short8 a0[4];
    #pragma unroll
    for (int mt = 0; mt < 4; ++mt)
        a0[mt] = *(const short8*)(wbase + mt * 128);

    f32x4 acc[4][2];
    #pragma unroll
    for (int mt = 0; mt < 4; ++mt)
        #pragma unroll
        for (int ti = 0; ti < 2; ++ti)
            acc[mt][ti] = (f32x4){0.f, 0.f, 0.f, 0.f};

    __syncthreads();   // B0: patch ready

    // conv: M=oa (A=W, wave owns 64 oa), N=i (B=patch), K=224
    #pragma unroll
    for (int s = 0; s < 7; ++s) {
        short8 a[4];
        #pragma unroll
        for (int mt = 0; mt < 4; ++mt)
            a[mt] = (s == 0) ? a0[mt]
                             : *(const short8*)(wbase + s * 8192 + mt * 128);
        const int kt = s * 4 + lg;
        int pos = 0;
        if (kt <= 24) { const int ky = kt / 5; pos = ky * 6 + (kt - ky * 5); }
        const int pr = pos + q;           // logical slot; phys = pr ^ (i&15)
        const short8 b0 = *(const short8*)(lds + lm * 512 + ((pr ^ lm) << 4));
        const short8 b1 = *(const short8*)(lds + (16 + lm) * 512 + ((pr ^ lm) << 4));
        __builtin_amdgcn_s_setprio(1);
        #pragma unroll
        for (int mt = 0; mt < 4; ++mt) {
            acc[mt][0] = __builtin_amdgcn_mfma_f32_16x16x32_bf16(a[mt], b0, acc[mt][0], 0, 0, 0);
            acc[mt][1] = __builtin_amdgcn_mfma_f32_16x16x32_bf16(a[mt], b1, acc[mt][1], 0, 0, 0);
        }
        __builtin_amdgcn_s_setprio(0);
    }

    // ---- per-wave transpose, 4 rounds (mh,ro); vtr region dedicated ----
    float v[4][8];                        // v[di][j]: i = 4ig+di, a = ig^j
    char* vtrb = lds + 18944 + wv * 2560; // [32 rows][80 B]
    #pragma unroll
    for (int mh = 0; mh < 2; ++mh)
        #pragma unroll
        for (int ro = 0; ro < 2; ++ro) {
            #pragma unroll
            for (int m2 = 0; m2 < 2; ++m2)
                #pragma unroll
                for (int r = 0; r < 4; ++r) {
                    const int row = (m2 << 4) + (lg << 2) + r;
                    *(float*)(vtrb + row * 80 +
                              ((((lm >> 2) + (row >> 3)) & 3) << 4) + ((lm & 3) << 2)) =
                        acc[mh * 2 + m2][ro][r];
                }
            if ((ig >> 2) == ro && (o_l >> 2) == mh) {
                const int cph = (((ig & 3) + (o_l & 3)) & 3) << 4;
                #pragma unroll
                for (int j = 0; j < 8; ++j) {
                    const int row = ((o_l & 3) << 3) + (ig ^ j);
                    const f32x4 r4 = *(const f32x4*)(vtrb + row * 80 + cph);
                    v[0][j] = r4[0]; v[1][j] = r4[1]; v[2][j] = r4[2]; v[3][j] = r4[3];
                }
            }
        }

    // routing arrays: [32 i][37] f32, stride 148 B (conflict-free: 20*ig+o
    // spreads the 8 ig-ranges over all 32 banks exactly 2-way)
    float* logits_q = (float*)(lds + q * 4736);
    float* route_q  = (float*)(lds + 9472 + q * 4736);
    const int rw_byte = ig * 592 + o * 4;                // [i=4ig+di][o], +di*148
    const int sm_byte = o * 148 + (ig << 4);             // row i=o, cols 4ig.., b128

    float lacc[4] = {0.f, 0.f, 0.f, 0.f};
    float actv = 0.f;

    #pragma unroll
    for (int it = 0; it < 3; ++it) {
        // ---- preact: pre(o, a=ig) ----
        float pre;
        if (it == 0) {
            float p[8];
            #pragma unroll
            for (int j = 0; j < 8; ++j)
                p[j] = (v[0][j] + v[1][j]) + (v[2][j] + v[3][j]);
            const float R = reduce_xpose8(p);
            pre = fmaf(fmaf(cb_own, 32.f, R), 1.f / 33.f, bias_own);
        } else {
            float r4[4];
            #pragma unroll
            for (int di = 0; di < 4; ++di)
                r4[di] = *(const float*)((char*)route_q + rw_byte + di * 148);
            float p[8];
            #pragma unroll
            for (int j = 0; j < 8; ++j) {
                float s = v[0][j] * r4[0];
                s = fmaf(v[1][j], r4[1], s);
                s = fmaf(v[2][j], r4[2], s);
                s = fmaf(v[3][j], r4[3], s);
                p[j] = s;
            }
            const float S_o = sum8((r4[0] + r4[1]) + (r4[2] + r4[3]));
            const float P = reduce_xpose8(p);
            pre = fmaf(cb_own, S_o, P) + bias_own;
        }

        // ---- squash over atoms ----
        const float ns = sum8(pre * pre);
        actv = pre * ns * __builtin_amdgcn_rsqf(ns) * __builtin_amdgcn_rcpf(1.f + ns);

        if (it < 2) {
            // act allgather in xor-slot order
            float ag[8];
            ag[0] = actv;
            ag[4] = swz_xor4(ag[0]);
            ag[2] = dpp_movf<0x4E>(ag[0]);
            ag[6] = dpp_movf<0x4E>(ag[4]);
            ag[1] = dpp_movf<0xB1>(ag[0]);
            ag[3] = dpp_movf<0xB1>(ag[2]);
            ag[5] = dpp_movf<0xB1>(ag[4]);
            ag[7] = dpp_movf<0xB1>(ag[6]);
            const float cbact = sum8(cb_own * actv);

            // logit update in registers
            #pragma unroll
            for (int di = 0; di < 4; ++di) {
                float d = cbact;
                #pragma unroll
                for (int j = 0; j < 8; ++j)
                    d = fmaf(v[di][j], ag[j], d);
                lacc[di] += d;
            }

            // B1 (iter0 only): all conv patch reads done before logits reuse region
            if (it == 0) __syncthreads();

            #pragma unroll
            for (int di = 0; di < 4; ++di)
                *(float*)((char*)logits_q + rw_byte + di * 148) = lacc[di];
            __syncthreads();   // B2/B4

            // leaky softmax over o for row i = o
            f32x4 e = *(const f32x4*)((char*)logits_q + sm_byte);
            float mx = fmaxf(fmaxf(e[0], e[1]), fmaxf(e[2], e[3]));
            mx = max8(fmaxf(mx, 0.f));                   // include leak logit 0
            e[0] = __expf(e[0] - mx); e[1] = __expf(e[1] - mx);
            e[2] = __expf(e[2] - mx); e[3] = __expf(e[3] - mx);
            const float ssum = sum8((e[0] + e[1]) + (e[2] + e[3])) + __expf(-mx);
            const float inv = __builtin_amdgcn_rcpf(ssum);
            e[0] *= inv; e[1] *= inv; e[2] *= inv; e[3] *= inv;
            *(f32x4*)((char*)route_q + sm_byte) = e;
            __syncthreads();   // B3/B5
        }
    }

    // out[b][o][h][w][a]: a = ig
    const int pix = (h << 5) + w0 + q;
    out[(((size_t)(((b << 5) + o) << 10) + pix) << 3) + ig] = actv;
}

extern "C" void kernel_launch(void* const* d_in, const int* in_sizes, int n_in,
                              void* d_out, int out_size, void* d_ws, size_t ws_size,
                              hipStream_t stream) {
    const float* x      = (const float*)d_in[0];
    const float* conv_w = (const float*)d_in[1];
    const float* conv_b = (const float*)d_in[2];
    const float* biases = (const float*)d_in[3];
    unsigned short* wp = (unsigned short*)d_ws;                     // 114,688 B
    unsigned short* xt = (unsigned short*)((char*)d_ws + 131072);   // 4 MB
    prep<<<dim3(480), dim3(256), 0, stream>>>(conv_w, x, wp, xt);
    capsule_mfma2<<<dim3(4096), dim3(512), 0, stream>>>(xt, wp, conv_b, biases, (float*)d_out);
}

// Round 12
// 62.974 us; speedup vs baseline: 4.2762x; 1.0426x over previous
//
#include <hip/hip_runtime.h>
#include <math.h>

// ConvCapsule R12 = R11 + transpose address hoisting.
// Transpose write addresses are identical across all 4 (mh,ro) rounds and
// collapse to TWO thread-constant bases (m2=0/1) + immediate r*80 offsets:
//   row(m2=0)=4lg+r -> row>>3 = lg>>1 ; row(m2=1)=16+4lg+r -> chunk ^= 2.
// Read base likewise thread-constant. Cuts ~110 VALU/wave of addressing.
// LDS map (39424 B): patch [0,16384) conv-phase; routing [0,18944) after B1
// (logits q*4736, route 9472+q*4736, [32][37] f32); vtr [18944,39424).

using short8 = __attribute__((ext_vector_type(8))) short;
using f32x4  = __attribute__((ext_vector_type(4))) float;

__device__ __forceinline__ unsigned short f2bf(float f) {
    unsigned u = __float_as_uint(f);
    return (unsigned short)((u + 0x7fffu + ((u >> 16) & 1u)) >> 16);  // RNE
}

template<int CTRL>
__device__ __forceinline__ float dpp_movf(float x) {
    return __int_as_float(__builtin_amdgcn_update_dpp(
        0, __float_as_int(x), CTRL, 0xF, 0xF, true));
}
__device__ __forceinline__ float swz_xor4(float x) {   // lane ^= 4
    return __int_as_float(__builtin_amdgcn_ds_swizzle(__float_as_int(x), 0x101F));
}
__device__ __forceinline__ float sum8(float x) {
    x += dpp_movf<0xB1>(x);
    x += dpp_movf<0x4E>(x);
    x += dpp_movf<0x141>(x);
    return x;
}
__device__ __forceinline__ float max8(float x) {
    x = fmaxf(x, dpp_movf<0xB1>(x));
    x = fmaxf(x, dpp_movf<0x4E>(x));
    x = fmaxf(x, dpp_movf<0x141>(x));
    return x;
}
// butterfly reduce-transpose over 8-lane group: p[j] holds partial for a=ig^j;
// returns full sum for a=ig.
__device__ __forceinline__ float reduce_xpose8(float p[8]) {
    p[0] += dpp_movf<0xB1>(p[1]);
    p[2] += dpp_movf<0xB1>(p[3]);
    p[4] += dpp_movf<0xB1>(p[5]);
    p[6] += dpp_movf<0xB1>(p[7]);
    p[0] += dpp_movf<0x4E>(p[2]);
    p[4] += dpp_movf<0x4E>(p[6]);
    p[0] += swz_xor4(p[4]);
    return p[0];
}

// ---------- merged prep: blocks [0,224) -> W bf16 repack; [224,480) -> x transpose ----------
__global__ __launch_bounds__(256)
void prep(const float* __restrict__ cw, const float* __restrict__ x,
          unsigned short* __restrict__ wp, unsigned short* __restrict__ xt) {
    __shared__ unsigned short tile[32 * 256];
    const int t = threadIdx.x;
    if (blockIdx.x < 224) {
        // W -> bf16, [s(7)][g(4)][oa(256)][j(8)], k = s*32+g*8+j
        const int idx = blockIdx.x * 256 + t;         // 57344 total
        const int j  = idx & 7;
        const int oa = (idx >> 3) & 255;
        const int g  = (idx >> 11) & 3;
        const int s  = idx >> 13;
        const int k  = s * 32 + g * 8 + j;
        wp[idx] = (k < 200) ? f2bf(cw[k * 256 + oa]) : (unsigned short)0;
        return;
    }
    // x -> bf16 transposed [b][y][x][i*8+ci]
    const int bid = blockIdx.x - 224;                 // 256 blocks
    const int b = bid >> 5, y = bid & 31;
    const float* src = x + (((size_t)((b << 8) + t)) << 10) + (y << 5);
    #pragma unroll
    for (int c = 0; c < 8; ++c) {
        float4 v = *(const float4*)(src + c * 4);
        tile[(c * 4 + 0) * 256 + t] = f2bf(v.x);
        tile[(c * 4 + 1) * 256 + t] = f2bf(v.y);
        tile[(c * 4 + 2) * 256 + t] = f2bf(v.z);
        tile[(c * 4 + 3) * 256 + t] = f2bf(v.w);
    }
    __syncthreads();
    unsigned short* dst = xt + ((size_t)bid << 13);
    #pragma unroll
    for (int c = 0; c < 4; ++c) {
        const int chunk = t + c * 256;
        *(short8*)(dst + chunk * 8) = *(const short8*)(&tile[chunk * 8]);
    }
}

// ---------- main fused kernel: 2 pixels / 512 threads / 8 waves ----------
__global__ __launch_bounds__(512, 4)
void capsule_mfma2(const unsigned short* __restrict__ xt,
                   const unsigned short* __restrict__ wp,
                   const float* __restrict__ conv_b,
                   const float* __restrict__ biases,
                   float* __restrict__ out)
{
    __shared__ __align__(16) char lds[39424];

    const int t   = threadIdx.x;
    const int blk = blockIdx.x;           // 4096
    const int b   = blk >> 9;
    const int rem = blk & 511;
    const int h   = rem >> 4;
    const int w0  = (rem & 15) << 1;      // pixels w0, w0+1

    // ---- stage patch: slot XOR-swizzled, row stride 512B ----
    for (int u = t; u < 960; u += 512) {
        const int i = u & 31, pos = u >> 5;          // pos in [0,30)
        const int ky = pos / 6, xl = pos - ky * 6;
        const int y = h + ky - 2, xx = w0 + xl - 2;
        short8 vv = {0, 0, 0, 0, 0, 0, 0, 0};
        if ((unsigned)y < 32u && (unsigned)xx < 32u)
            vv = *(const short8*)(xt + (((size_t)(((b << 5) + y) << 5) + xx) << 8) + i * 8);
        *(short8*)(lds + i * 512 + ((pos ^ (i & 15)) << 4)) = vv;
    }

    const int l  = t & 63, wv = t >> 6;   // 8 waves
    const int lm = l & 15, lg = l >> 4;   // conv C-layout coords
    const int o_l = l >> 3, ig = l & 7;   // routing coords
    const int o  = ((wv & 3) << 3) + o_l; // capsule 0..31
    const int q  = wv >> 2;               // pixel

    const float cb_own   = conv_b[t & 255];
    const float bias_own = biases[t & 255];

    // W s=0 prefetch (hides L2 latency under the staging barrier)
    const unsigned short* wbase = wp + lg * 2048 + ((((wv & 3) << 6) + lm) << 3);
    short8 a0[4];
    #pragma unroll
    for (int mt = 0; mt < 4; ++mt)
        a0[mt] = *(const short8*)(wbase + mt * 128);

    f32x4 acc[4][2];
    #pragma unroll
    for (int mt = 0; mt < 4; ++mt)
        #pragma unroll
        for (int ti = 0; ti < 2; ++ti)
            acc[mt][ti] = (f32x4){0.f, 0.f, 0.f, 0.f};

    __syncthreads();   // B0: patch ready

    // conv: M=oa (A=W, wave owns 64 oa), N=i (B=patch), K=224
    #pragma unroll
    for (int s = 0; s < 7; ++s) {
        short8 a[4];
        #pragma unroll
        for (int mt = 0; mt < 4; ++mt)
            a[mt] = (s == 0) ? a0[mt]
                             : *(const short8*)(wbase + s * 8192 + mt * 128);
        const int kt = s * 4 + lg;
        int pos = 0;
        if (kt <= 24) { const int ky = kt / 5; pos = ky * 6 + (kt - ky * 5); }
        const int pr = pos + q;           // logical slot; phys = pr ^ (i&15)
        const short8 b0 = *(const short8*)(lds + lm * 512 + ((pr ^ lm) << 4));
        const short8 b1 = *(const short8*)(lds + (16 + lm) * 512 + ((pr ^ lm) << 4));
        __builtin_amdgcn_s_setprio(1);
        #pragma unroll
        for (int mt = 0; mt < 4; ++mt) {
            acc[mt][0] = __builtin_amdgcn_mfma_f32_16x16x32_bf16(a[mt], b0, acc[mt][0], 0, 0, 0);
            acc[mt][1] = __builtin_amdgcn_mfma_f32_16x16x32_bf16(a[mt], b1, acc[mt][1], 0, 0, 0);
        }
        __builtin_amdgcn_s_setprio(0);
    }

    // ---- per-wave transpose, 4 rounds (mh,ro); vtr region dedicated ----
    // Hoisted addressing: write addresses identical across rounds ->
    //   m2=0 rows 4lg+r   : chunk0 = ((lm>>2)+(lg>>1))&3
    //   m2=1 rows 16+4lg+r: chunk  = chunk0^2
    float v[4][8];                        // v[di][j]: i = 4ig+di, a = ig^j
    char* vtrb = lds + 18944 + wv * 2560; // [32 rows][80 B]
    const int chunk0 = ((lm >> 2) + (lg >> 1)) & 3;
    char* wb0 = vtrb + (lg << 2) * 80 + (chunk0 << 4) + ((lm & 3) << 2);
    char* wb1 = vtrb + (16 + (lg << 2)) * 80 + ((chunk0 ^ 2) << 4) + ((lm & 3) << 2);
    const char* rb = vtrb + ((o_l & 3) << 3) * 80 + ((((ig & 3) + (o_l & 3)) & 3) << 4);
    #pragma unroll
    for (int mh = 0; mh < 2; ++mh)
        #pragma unroll
        for (int ro = 0; ro < 2; ++ro) {
            #pragma unroll
            for (int r = 0; r < 4; ++r) {
                *(float*)(wb0 + r * 80) = acc[mh * 2 + 0][ro][r];
                *(float*)(wb1 + r * 80) = acc[mh * 2 + 1][ro][r];
            }
            if ((ig >> 2) == ro && (o_l >> 2) == mh) {
                #pragma unroll
                for (int j = 0; j < 8; ++j) {
                    const f32x4 r4 = *(const f32x4*)(rb + (ig ^ j) * 80);
                    v[0][j] = r4[0]; v[1][j] = r4[1]; v[2][j] = r4[2]; v[3][j] = r4[3];
                }
            }
        }

    // routing arrays: [32 i][37] f32, stride 148 B (2-way max: banks 20*ig+o)
    float* logits_q = (float*)(lds + q * 4736);
    float* route_q  = (float*)(lds + 9472 + q * 4736);
    const int rw_byte = ig * 592 + o * 4;                // [i=4ig+di][o], +di*148
    const int sm_byte = o * 148 + (ig << 4);             // row i=o, cols 4ig.., b128

    float lacc[4] = {0.f, 0.f, 0.f, 0.f};
    float actv = 0.f;

    #pragma unroll
    for (int it = 0; it < 3; ++it) {
        // ---- preact: pre(o, a=ig) ----
        float pre;
        if (it == 0) {
            float p[8];
            #pragma unroll
            for (int j = 0; j < 8; ++j)
                p[j] = (v[0][j] + v[1][j]) + (v[2][j] + v[3][j]);
            const float R = reduce_xpose8(p);
            pre = fmaf(fmaf(cb_own, 32.f, R), 1.f / 33.f, bias_own);
        } else {
            float r4[4];
            #pragma unroll
            for (int di = 0; di < 4; ++di)
                r4[di] = *(const float*)((char*)route_q + rw_byte + di * 148);
            float p[8];
            #pragma unroll
            for (int j = 0; j < 8; ++j) {
                float s = v[0][j] * r4[0];
                s = fmaf(v[1][j], r4[1], s);
                s = fmaf(v[2][j], r4[2], s);
                s = fmaf(v[3][j], r4[3], s);
                p[j] = s;
            }
            const float S_o = sum8((r4[0] + r4[1]) + (r4[2] + r4[3]));
            const float P = reduce_xpose8(p);
            pre = fmaf(cb_own, S_o, P) + bias_own;
        }

        // ---- squash over atoms ----
        const float ns = sum8(pre * pre);
        actv = pre * ns * __builtin_amdgcn_rsqf(ns) * __builtin_amdgcn_rcpf(1.f + ns);

        if (it < 2) {
            // act allgather in xor-slot order
            float ag[8];
            ag[0] = actv;
            ag[4] = swz_xor4(ag[0]);
            ag[2] = dpp_movf<0x4E>(ag[0]);
            ag[6] = dpp_movf<0x4E>(ag[4]);
            ag[1] = dpp_movf<0xB1>(ag[0]);
            ag[3] = dpp_movf<0xB1>(ag[2]);
            ag[5] = dpp_movf<0xB1>(ag[4]);
            ag[7] = dpp_movf<0xB1>(ag[6]);
            const float cbact = sum8(cb_own * actv);

            // logit update in registers
            #pragma unroll
            for (int di = 0; di < 4; ++di) {
                float d = cbact;
                #pragma unroll
                for (int j = 0; j < 8; ++j)
                    d = fmaf(v[di][j], ag[j], d);
                lacc[di] += d;
            }

            // B1 (iter0 only): all conv patch reads done before logits reuse region
            if (it == 0) __syncthreads();

            #pragma unroll
            for (int di = 0; di < 4; ++di)
                *(float*)((char*)logits_q + rw_byte + di * 148) = lacc[di];
            __syncthreads();   // B2/B4

            // leaky softmax over o for row i = o
            f32x4 e = *(const f32x4*)((char*)logits_q + sm_byte);
            float mx = fmaxf(fmaxf(e[0], e[1]), fmaxf(e[2], e[3]));
            mx = max8(fmaxf(mx, 0.f));                   // include leak logit 0
            e[0] = __expf(e[0] - mx); e[1] = __expf(e[1] - mx);
            e[2] = __expf(e[2] - mx); e[3] = __expf(e[3] - mx);
            const float ssum = sum8((e[0] + e[1]) + (e[2] + e[3])) + __expf(-mx);
            const float inv = __builtin_amdgcn_rcpf(ssum);
            e[0] *= inv; e[1] *= inv; e[2] *= inv; e[3] *= inv;
            *(f32x4*)((char*)route_q + sm_byte) = e;
            __syncthreads();   // B3/B5
        }
    }

    // out[b][o][h][w][a]: a = ig
    const int pix = (h << 5) + w0 + q;
    out[(((size_t)(((b << 5) + o) << 10) + pix) << 3) + ig] = actv;
}

extern "C" void kernel_launch(void* const* d_in, const int* in_sizes, int n_in,
                              void* d_out, int out_size, void* d_ws, size_t ws_size,
                              hipStream_t stream) {
    const float* x      = (const float*)d_in[0];
    const float* conv_w = (const float*)d_in[1];
    const float* conv_b = (const float*)d_in[2];
    const float* biases = (const float*)d_in[3];
    unsigned short* wp = (unsigned short*)d_ws;                     // 114,688 B
    unsigned short* xt = (unsigned short*)((char*)d_ws + 131072);   // 4 MB
    prep<<<dim3(480), dim3(256), 0, stream>>>(conv_w, x, wp, xt);
    capsule_mfma2<<<dim3(4096), dim3(512), 0, stream>>>(xt, wp, conv_b, biases, (float*)d_out);
}